// Round 1
// baseline (109.017 us; speedup 1.0000x reference)
//
#include <hip/hip_runtime.h>

// SpectralConv2D: out[f,row,col,q] = relu( sum_{k=0..8} Lambda[phi] * Yflat[phi*128+q] )
// phi = (3*row+block)*378 + (3*col+j);  Yflat is flattened (C=128,R=378,S=378) with
// Y[c,r,s] = raw[c*16384 + (r/3+r%3)*128 + (s/3+s%3)];  broadcast over f=0..63.

#define L_TOT 15876  // 126*126

__global__ __launch_bounds__(128) void spectral_base_kernel(
    const float* __restrict__ x, const float* __restrict__ lam,
    float* __restrict__ out)
{
    __shared__ float s[128];
    const int l = blockIdx.x;          // 0..15875
    const int t = threadIdx.x;         // 0..127 (= q)
    const int row = l / 126;
    const int col = l - row * 126;

    float acc = 0.0f;
#pragma unroll
    for (int b3 = 0; b3 < 3; ++b3) {
#pragma unroll
        for (int j = 0; j < 3; ++j) {
            const unsigned phi = (unsigned)((3 * row + b3) * 378 + 3 * col + j);
            const unsigned n   = phi * 128u + (unsigned)t;      // < 18.3M, fits u32
            const unsigned c   = n / 142884u;                   // 378*378
            const unsigned rem = n - c * 142884u;
            const unsigned r   = rem / 378u;
            const unsigned ss  = rem - r * 378u;
            const unsigned src = c * 16384u + (r / 3u + r % 3u) * 128u + (ss / 3u + ss % 3u);
            acc = fmaf(x[src], lam[phi], acc);
        }
    }
    s[t] = fmaxf(acc, 0.0f);
    __syncthreads();

    // Broadcast to 64 filter copies with float4 stores.
    const float4* s4 = (const float4*)s;
    float4* out4 = (float4*)out;
    const size_t lbase = (size_t)l * 32;          // 32 float4 per (l) row
#pragma unroll
    for (int i = 0; i < 16; ++i) {
        const int idx = i * 128 + t;              // 0..2047
        const int f = idx >> 5;                   // filter 0..63
        const int v = idx & 31;                   // float4 index within row
        out4[(size_t)f * (L_TOT * 32) + lbase + v] = s4[v];
    }
}

extern "C" void kernel_launch(void* const* d_in, const int* in_sizes, int n_in,
                              void* d_out, int out_size, void* d_ws, size_t ws_size,
                              hipStream_t stream) {
    const float* x   = (const float*)d_in[0];   // (1,128,128,128) f32
    const float* lam = (const float*)d_in[1];   // (1, 142884) f32
    float* out = (float*)d_out;                 // (64,126,126,128) f32

    spectral_base_kernel<<<L_TOT, 128, 0, stream>>>(x, lam, out);
}

// Round 3
// 101.527 us; speedup vs baseline: 1.0738x; 1.0738x over previous
//
#include <hip/hip_runtime.h>

// SpectralConv2D: out[f,row,col,q] = relu( sum_{k=0..8} Lambda[phi] * Yflat[phi*128+q] )
// phi = (3*row+block)*378 + (3*col+j);  Yflat is flattened (C=128,R=378,S=378) with
// Y[c,r,s] = raw[c*16384 + (r/3+r%3)*128 + (s/3+s%3)];  broadcast over f=0..63.

#define L_TOT 15876   // 126*126
#define L32   (L_TOT * 32)   // float4 per filter plane

typedef float f4 __attribute__((ext_vector_type(4)));  // native vector for nontemporal builtin

__global__ __launch_bounds__(256) void spectral_kernel(
    const float* __restrict__ x, const float* __restrict__ lam,
    float* __restrict__ out)
{
    __shared__ float s[256];           // two rows of 128
    const int t  = threadIdx.x;        // 0..255
    const int l0 = blockIdx.x * 2;     // first of two consecutive l
    const int li = t >> 7;             // 0 or 1
    const int q  = t & 127;
    const int l  = l0 + li;
    const int row = l / 126;
    const int col = l - row * 126;

    float acc = 0.0f;
#pragma unroll
    for (int b3 = 0; b3 < 3; ++b3) {
#pragma unroll
        for (int j = 0; j < 3; ++j) {
            const unsigned phi = (unsigned)((3 * row + b3) * 378 + 3 * col + j);
            const unsigned n   = phi * 128u + (unsigned)q;      // < 18.3M, fits u32
            const unsigned c   = n / 142884u;                   // 378*378
            const unsigned rem = n - c * 142884u;
            const unsigned r   = rem / 378u;
            const unsigned ss  = rem - r * 378u;
            const unsigned src = c * 16384u + (r / 3u + r % 3u) * 128u + (ss / 3u + ss % 3u);
            acc = fmaf(x[src], lam[phi], acc);
        }
    }
    s[t] = fmaxf(acc, 0.0f);
    __syncthreads();

    // Broadcast to 64 filter copies; one wave writes one 1KB contiguous chunk.
    const f4* s4 = (const f4*)s;       // 64 f4 covering both l rows
    f4* out4 = (f4*)out;
    const size_t lbase = (size_t)l0 * 32;
#pragma unroll
    for (int i = 0; i < 16; ++i) {
        const int idx = i * 256 + t;       // 0..4095
        const int f = idx >> 6;            // filter 0..63
        const int v = idx & 63;            // f4 index within 2-row chunk
        __builtin_nontemporal_store(s4[v], &out4[(size_t)f * L32 + lbase + v]);
    }
}

extern "C" void kernel_launch(void* const* d_in, const int* in_sizes, int n_in,
                              void* d_out, int out_size, void* d_ws, size_t ws_size,
                              hipStream_t stream) {
    const float* x   = (const float*)d_in[0];   // (1,128,128,128) f32
    const float* lam = (const float*)d_in[1];   // (1, 142884) f32
    float* out = (float*)d_out;                 // (64,126,126,128) f32

    spectral_kernel<<<L_TOT / 2, 256, 0, stream>>>(x, lam, out);
}

// Round 4
// 99.684 us; speedup vs baseline: 1.0936x; 1.0185x over previous
//
#include <hip/hip_runtime.h>

// SpectralConv2D: out[f,row,col,q] = relu( sum_{k=0..8} Lambda[phi] * Yflat[phi*128+q] )
// phi = (3*row+block)*378 + (3*col+j);  Yflat is flattened (C=128,R=378,S=378) with
// Y[c,r,s] = raw[c*16384 + (r/3+r%3)*128 + (s/3+s%3)];  broadcast over f=0..63.

#define L_TOT 15876   // 126*126
#define L32   (L_TOT * 32)   // f4 per filter plane
#define LPB   4              // l-rows per block

typedef float f4 __attribute__((ext_vector_type(4)));

__global__ __launch_bounds__(256) void spectral_kernel(
    const float* __restrict__ x, const float* __restrict__ lam,
    float* __restrict__ out)
{
    __shared__ float s[LPB * 128];     // 4 rows of 128
    const int t  = threadIdx.x;        // 0..255
    const int l0 = blockIdx.x * LPB;
    const int q  = t & 127;

    // Each thread computes rows (t>>7) and (t>>7)+2.
#pragma unroll
    for (int li = (t >> 7); li < LPB; li += 2) {
        const int l = l0 + li;
        const int row = l / 126;
        const int col = l - row * 126;
        float acc = 0.0f;
#pragma unroll
        for (int b3 = 0; b3 < 3; ++b3) {
#pragma unroll
            for (int j = 0; j < 3; ++j) {
                const unsigned phi = (unsigned)((3 * row + b3) * 378 + 3 * col + j);
                const unsigned n   = phi * 128u + (unsigned)q;  // fits u32
                const unsigned c   = n / 142884u;               // 378*378
                const unsigned rem = n - c * 142884u;
                const unsigned r   = rem / 378u;
                const unsigned ss  = rem - r * 378u;
                const unsigned src = c * 16384u + (r / 3u + r % 3u) * 128u + (ss / 3u + ss % 3u);
                acc = fmaf(x[src], lam[phi], acc);
            }
        }
        s[li * 128 + q] = fmaxf(acc, 0.0f);
    }
    __syncthreads();

    // Broadcast to 64 filter planes. Iteration i writes filters 2i,2i+1 as two
    // full 2KB contiguous chunks (128 f4 each).
    const f4* s4 = (const f4*)s;       // 128 f4 covering the 4 rows
    f4* out4 = (f4*)out;
    const size_t lbase = (size_t)l0 * 32;
#pragma unroll
    for (int i = 0; i < 32; ++i) {
        const int idx = i * 256 + t;   // 0..8191
        const int f = idx >> 7;        // filter 0..63
        const int v = idx & 127;       // f4 index within 4-row chunk
        __builtin_nontemporal_store(s4[v], &out4[(size_t)f * L32 + lbase + v]);
    }
}

extern "C" void kernel_launch(void* const* d_in, const int* in_sizes, int n_in,
                              void* d_out, int out_size, void* d_ws, size_t ws_size,
                              hipStream_t stream) {
    const float* x   = (const float*)d_in[0];   // (1,128,128,128) f32
    const float* lam = (const float*)d_in[1];   // (1, 142884) f32
    float* out = (float*)d_out;                 // (64,126,126,128) f32

    spectral_kernel<<<L_TOT / LPB, 256, 0, stream>>>(x, lam, out);
}